// Round 2
// baseline (181.820 us; speedup 1.0000x reference)
//
#include <hip/hip_runtime.h>
#include <hip/hip_bf16.h>
#include <math.h>

#define BATCH  2
#define S_LEN  2048
#define DMODEL 1024
#define NH     16
#define DHEAD  64

typedef __attribute__((ext_vector_type(8))) short bf16x8;   // 8 bf16 = 4 VGPRs
typedef __attribute__((ext_vector_type(4))) float f32x4;

#define MFMA16(a,b,c) __builtin_amdgcn_mfma_f32_16x16x32_bf16((a),(b),(c),0,0,0)

// Q pre-scale: (1/sqrt(64)) * log2(e) so attention uses exp2 directly
#define QSCALE 0.18033688011110793f
#define EXP2F(x) __builtin_amdgcn_exp2f(x)

__device__ __forceinline__ unsigned int pkbf(float a, float b) {
    __hip_bfloat162 h = __float22bfloat162_rn(make_float2(a, b));
    union { __hip_bfloat162 h; unsigned int u; } v; v.h = h; return v.u;
}
__device__ __forceinline__ void gl2lds16(const void* g, void* l) {
    __builtin_amdgcn_global_load_lds(
        (const __attribute__((address_space(1))) void*)(g),
        (__attribute__((address_space(3))) void*)(l), 16, 0, 0);
}

// ---------------------------------------------------------------------------
// Single fused fp32->bf16 convert for Q, W_Q|W_K|W_V, mask. 8 elems/unit.
// Layout: units [0,524288) = Q; [524288,917504) = W (3x131072); tail = mask.
// ---------------------------------------------------------------------------
__global__ __launch_bounds__(256) void cvt_all(
    const float* __restrict__ Q,  const float* __restrict__ WQ,
    const float* __restrict__ WK, const float* __restrict__ WV,
    const float* __restrict__ msk,
    unsigned short* __restrict__ Qbf, unsigned short* __restrict__ Wbf,
    unsigned short* __restrict__ mbf)
{
    int i = blockIdx.x * blockDim.x + threadIdx.x;   // grid covers 918016 units
    const float* src;
    unsigned short* dst;
    int off;
    if (i < 524288) {
        src = Q; dst = Qbf; off = i;
    } else if (i < 917504) {
        int j = i - 524288;                  // [0, 393216)
        int which = j >> 17;                 // /131072
        src = (which == 0) ? WQ : ((which == 1) ? WK : WV);
        dst = Wbf + ((size_t)which << 20);   // which * 1048576
        off = j & 131071;
    } else {
        int j = i - 917504;
        if (j >= 512) return;
        src = msk; dst = mbf; off = j;
    }
    float4 a = ((const float4*)src)[2*off];
    float4 b = ((const float4*)src)[2*off + 1];
    uint4 o;
    o.x = pkbf(a.x, a.y); o.y = pkbf(a.z, a.w);
    o.z = pkbf(b.x, b.y); o.w = pkbf(b.z, b.w);
    ((uint4*)dst)[off] = o;
}

// ---------------------------------------------------------------------------
// Projection GEMM with folds:
//   z=0 -> qw [b,h,s,dk], output scaled by QSCALE (1/sqrt(dk) * log2e)
//   z=1 -> kw [b,h,s,dk]
//   z=2 -> vt [b,h,dv,s], output multiplied by mask[b][s] (V' = mask*V)
// 128x128 tile, BK=64, 4 waves, double-buffered LDS, 2-phase pipeline.
// XOR-swizzled LDS (linear gl2lds dest + pre-swizzled global source + swz read).
// XCD-bijective block remap (768 = 8*96).
// ---------------------------------------------------------------------------
__global__ __launch_bounds__(256) void proj_mfma(
    const unsigned short* __restrict__ Abf,   // [4096][1024]
    const unsigned short* __restrict__ Wbf,   // [3][1024][1024]
    const float* __restrict__ bQ, const float* __restrict__ bK,
    const float* __restrict__ bV, const float* __restrict__ mask,
    unsigned short* __restrict__ qw, unsigned short* __restrict__ kw,
    unsigned short* __restrict__ vt)
{
    __shared__ union {
        struct { unsigned short At[2][128*64]; unsigned short Bt[2][128*64]; } s; // 64 KB
        unsigned short Ct[128*132];     // epilogue transpose tile (33.8 KB, aliased)
    } sm;

    const int tid  = threadIdx.x;
    const int lane = tid & 63;
    const int wv   = tid >> 6;
    const int wm   = (wv >> 1) * 64;
    const int wn   = (wv & 1) * 64;
    const int q15  = lane & 15;
    const int quad = lane >> 4;

    // XCD-aware bijective remap: f = x + 8y + 256z in [0,768); xcd = f%8 owns
    // logical ids [xcd*96, xcd*96+96) = contiguous (z, m-panel) ranges.
    const int f  = blockIdx.x + (blockIdx.y << 3) + (blockIdx.z << 8);
    const int l  = (f & 7) * 96 + (f >> 3);
    const int z  = l >> 8;
    const int lr = l & 255;
    const int n0 = (lr & 7) * 128;
    const int m0 = (lr >> 3) * 128;

    const unsigned short* Wz = Wbf + (size_t)z * DMODEL * DMODEL;
    const float* bias = (z == 0) ? bQ : ((z == 1) ? bK : bV);

    f32x4 zero4 = {0.f, 0.f, 0.f, 0.f};
    f32x4 acc[4][4];
    #pragma unroll
    for (int i = 0; i < 4; ++i)
        #pragma unroll
        for (int j = 0; j < 4; ++j) acc[i][j] = zero4;

    #define STAGE_PROJ(BUF, K0)                                                \
        _Pragma("unroll")                                                      \
        for (int c = 0; c < 4; ++c) {                                          \
            int o   = tid * 16 + c * 4096;                                     \
            int row = o >> 7;                                                  \
            int lb  = (o & 127) ^ ((row & 7) << 4);                            \
            gl2lds16(Abf + (size_t)(m0 + row) * DMODEL + (K0) + (lb >> 1),     \
                     (char*)sm.s.At[BUF] + o);                                 \
            gl2lds16(Wz  + (size_t)(n0 + row) * DMODEL + (K0) + (lb >> 1),     \
                     (char*)sm.s.Bt[BUF] + o);                                 \
        }

    // prologue: fill buffer 0
    STAGE_PROJ(0, 0)
    __syncthreads();

    const int sw = (q15 & 7) << 4;   // read-side swizzle ((row&7)<<4; row&7 == q15&7)

    for (int t = 0; t < 16; ++t) {
        const int buf = t & 1;
        if (t < 15) { STAGE_PROJ(buf ^ 1, (t + 1) * 64) }   // in flight under compute

        bf16x8 af[4][2], bfr[4][2];
        #pragma unroll
        for (int i = 0; i < 4; ++i) {
            const char* pa = (const char*)sm.s.At[buf] + (wm + i*16 + q15) * 128;
            const char* pb = (const char*)sm.s.Bt[buf] + (wn + i*16 + q15) * 128;
            af[i][0]  = *(const bf16x8*)(pa + (( 0 + quad*16) ^ sw));
            af[i][1]  = *(const bf16x8*)(pa + ((64 + quad*16) ^ sw));
            bfr[i][0] = *(const bf16x8*)(pb + (( 0 + quad*16) ^ sw));
            bfr[i][1] = *(const bf16x8*)(pb + ((64 + quad*16) ^ sw));
        }

        if (z < 2) {
            #pragma unroll
            for (int ks = 0; ks < 2; ++ks)
                #pragma unroll
                for (int i = 0; i < 4; ++i)
                    #pragma unroll
                    for (int j = 0; j < 4; ++j)
                        acc[i][j] = MFMA16(bfr[j][ks], af[i][ks], acc[i][j]);
        } else {
            #pragma unroll
            for (int ks = 0; ks < 2; ++ks)
                #pragma unroll
                for (int i = 0; i < 4; ++i)
                    #pragma unroll
                    for (int j = 0; j < 4; ++j)
                        acc[i][j] = MFMA16(af[i][ks], bfr[j][ks], acc[i][j]);
        }
        __syncthreads();   // drains stage(t+1) vmcnt + fences buf reuse
    }
    #undef STAGE_PROJ

    // epilogue (Ct aliases At/Bt; last barrier above fenced all reads)
    if (z < 2) {
        const float qs = (z == 0) ? QSCALE : 1.0f;
        #pragma unroll
        for (int i = 0; i < 4; ++i) {
            int ml = wm + i*16 + q15;
            #pragma unroll
            for (int j = 0; j < 4; ++j) {
                int nl = wn + j*16 + quad*4;
                float4 b4 = *(const float4*)(bias + n0 + nl);
                f32x4 v = acc[i][j];
                uint2 u;
                u.x = pkbf((v.x + b4.x)*qs, (v.y + b4.y)*qs);
                u.y = pkbf((v.z + b4.z)*qs, (v.w + b4.w)*qs);
                *(uint2*)&sm.Ct[ml*132 + nl] = u;
            }
        }
    } else {
        #pragma unroll
        for (int i = 0; i < 4; ++i) {
            int ml = wm + i*16 + quad*4;
            int sg = m0 + ml;
            int b2 = sg >> 11, s0g = sg & 2047;
            float4 mk4 = *(const float4*)(mask + (size_t)b2*S_LEN + s0g);
            #pragma unroll
            for (int j = 0; j < 4; ++j) {
                int nl = wn + j*16 + q15;
                float bv = bias[n0 + nl];
                f32x4 v = acc[i][j];
                uint2 u;
                u.x = pkbf((v.x + bv)*mk4.x, (v.y + bv)*mk4.y);
                u.y = pkbf((v.z + bv)*mk4.z, (v.w + bv)*mk4.w);
                *(uint2*)&sm.Ct[nl*132 + ml] = u;
            }
        }
    }
    __syncthreads();

    {
        int row  = tid >> 1;
        int half = (tid & 1) * 64;
        const uint4* src = (const uint4*)&sm.Ct[row*132 + half];
        unsigned short* dst;
        if (z < 2) {
            unsigned short* outp = (z == 0) ? qw : kw;
            int mg = m0 + row;  int b2 = mg >> 11, s = mg & 2047;
            int n  = n0 + half; int hh = n >> 6;
            dst = outp + (((size_t)b2*NH + hh)*S_LEN + s)*DHEAD;
        } else {
            int n  = n0 + row;  int hh = n >> 6, dv = n & 63;
            int b2 = m0 >> 11, s0 = m0 & 2047;
            dst = vt + (((size_t)b2*NH + hh)*DHEAD + dv)*S_LEN + s0 + half;
        }
        #pragma unroll
        for (int c = 0; c < 8; ++c) ((uint4*)dst)[c] = src[c];
    }
}

// ---------------------------------------------------------------------------
// Attention: block = 64 queries x (h, b); 4 waves x 16 queries.
// Grid = 1024 blocks (4 blocks/CU resident, 16 waves/CU = 4/SIMD) — was 512
// (2/CU): the kernel is latency-bound, occupancy doubled via finer q-split.
// XCD-bijective remap: 1024 = 8*128; each XCD owns 4 complete heads so its
// K/V working set (4 x 512 KB = 2 MB) is L2-resident despite 2x logical reads.
// K staged into LDS with rows PERMUTED by lambda(key) so the QK C-layout,
// exp'd and packed, IS the PV A-fragment in registers (no P LDS round-trip).
//   lambda(key) = (key>>5)*32 + ((key>>2)&1)*16 + ((key>>3)&3)*4 + (key&3)
// Q pre-scaled by QSCALE -> scores already in log2 domain -> v_exp_f32.
// V pre-multiplied by mask; denominator = P @ mask via MFMA.
// s_setprio(1) wraps the MFMA clusters (T5; waves of 4 independent blocks
// are at different phases -> scheduler can favor MFMA-entering waves).
// ---------------------------------------------------------------------------
__global__ __launch_bounds__(256, 4) void attn_mfma(
    const unsigned short* __restrict__ qw, const unsigned short* __restrict__ kw,
    const unsigned short* __restrict__ vt, const unsigned short* __restrict__ mbf,
    float* __restrict__ out)
{
    __shared__ __align__(16) unsigned short Ks[2][64][72];   // [perm key][d]
    __shared__ __align__(16) unsigned short Vs[2][64][72];   // [dv][key]
    __shared__ __align__(16) unsigned short Ms[2][72];       // mask bf16

    const int tid  = threadIdx.x;
    const int lane = tid & 63;
    const int wv   = tid >> 6;
    const int q15  = lane & 15;
    const int quad = lane >> 4;

    // XCD-bijective remap (1024 blocks, 1024%8==0): orig%8 = XCD; XCD c owns
    // lid in [c*128, c*128+128) = heads [c*4, c*4+4), all 32 q-blocks of each.
    const int orig = blockIdx.x + (blockIdx.y << 5) + (blockIdx.z << 9);
    const int lid  = (orig & 7) * 128 + (orig >> 3);
    const int q0   = (lid & 31) * 64;
    const int head = lid >> 5;          // [0,32)
    const int h    = head & 15;
    const int b    = head >> 4;

    const size_t headoff = ((size_t)b * NH + h) * S_LEN * DHEAD;
    const unsigned short* qb = qw + headoff;
    const unsigned short* kb = kw + headoff;
    const unsigned short* vb = vt + headoff;          // [dv][s]
    const unsigned short* mb = mbf + (size_t)b * S_LEN;

    // Q fragments (B-operand): B[k=d at quad*8+j][n=query at lane&15]
    bf16x8 qf[2];
    {
        const unsigned short* qr = qb + (size_t)(q0 + wv*16 + q15)*DHEAD;
        qf[0] = *(const bf16x8*)(qr + quad*8);
        qf[1] = *(const bf16x8*)(qr + 32 + quad*8);
    }

    const int srow = tid >> 3;          // 0..31 (key row for staging)
    const int scol = (tid & 7) * 8;     // 0..56
    // permuted LDS row for K (srow in [0,32); +32 row adds +32 to lambda)
    const int prow = ((srow >> 2) & 1) * 16 + ((srow >> 3) & 3) * 4 + (srow & 3);

    f32x4 zero4 = {0.f, 0.f, 0.f, 0.f};
    f32x4 oacc[4];
    f32x4 dacc = zero4;
    #pragma unroll
    for (int nj = 0; nj < 4; ++nj) oacc[nj] = zero4;

    // prologue: prefetch tile 0 into registers
    uint4 kr0, kr1, vr0, vr1, mr = {0,0,0,0};
    kr0 = *(const uint4*)(kb + (size_t)(srow)     *DHEAD + scol);
    kr1 = *(const uint4*)(kb + (size_t)(srow + 32)*DHEAD + scol);
    vr0 = *(const uint4*)(vb + (size_t)(srow)     *S_LEN + scol);
    vr1 = *(const uint4*)(vb + (size_t)(srow + 32)*S_LEN + scol);
    if (tid < 8) mr = *(const uint4*)(mb + tid*8);

    for (int t = 0; t < 32; ++t) {
        const int buf = t & 1;
        const int k0  = t * 64;
        // commit staged regs to LDS[buf]
        *(uint4*)&Ks[buf][prow][scol]      = kr0;
        *(uint4*)&Ks[buf][prow + 32][scol] = kr1;
        *(uint4*)&Vs[buf][srow][scol]      = vr0;
        *(uint4*)&Vs[buf][srow + 32][scol] = vr1;
        if (tid < 8) *(uint4*)&Ms[buf][tid*8] = mr;
        // issue prefetch for tile t+1 (clamped; overlaps compute below)
        const int kn = (t < 31) ? k0 + 64 : 0;
        kr0 = *(const uint4*)(kb + (size_t)(kn + srow)     *DHEAD + scol);
        kr1 = *(const uint4*)(kb + (size_t)(kn + srow + 32)*DHEAD + scol);
        vr0 = *(const uint4*)(vb + (size_t)(srow)     *S_LEN + kn + scol);
        vr1 = *(const uint4*)(vb + (size_t)(srow + 32)*S_LEN + kn + scol);
        if (tid < 8) mr = *(const uint4*)(mb + kn + tid*8);
        __syncthreads();

        // ---- QK^T: 4 tiles; tile ks reg r = key quad*8+r+4*(ks&1)+32*(ks>>1)
        f32x4 s[4];
        __builtin_amdgcn_s_setprio(1);
        #pragma unroll
        for (int ks = 0; ks < 4; ++ks) {
            bf16x8 kf0 = *(const bf16x8*)&Ks[buf][ks*16 + q15][quad*8];
            bf16x8 kf1 = *(const bf16x8*)&Ks[buf][ks*16 + q15][32 + quad*8];
            f32x4 a = MFMA16(kf0, qf[0], zero4);
            s[ks]   = MFMA16(kf1, qf[1], a);
        }
        __builtin_amdgcn_s_setprio(0);
        // ---- exp2 + pack: registers ARE the PV A-fragments ----
        bf16x8 pf[2];
        {
            uint4 u0, u1;
            u0.x = pkbf(EXP2F(s[0][0]), EXP2F(s[0][1]));
            u0.y = pkbf(EXP2F(s[0][2]), EXP2F(s[0][3]));
            u0.z = pkbf(EXP2F(s[1][0]), EXP2F(s[1][1]));
            u0.w = pkbf(EXP2F(s[1][2]), EXP2F(s[1][3]));
            u1.x = pkbf(EXP2F(s[2][0]), EXP2F(s[2][1]));
            u1.y = pkbf(EXP2F(s[2][2]), EXP2F(s[2][3]));
            u1.z = pkbf(EXP2F(s[3][0]), EXP2F(s[3][1]));
            u1.w = pkbf(EXP2F(s[3][2]), EXP2F(s[3][3]));
            union { uint4 u; bf16x8 h; } c0, c1;
            c0.u = u0; c1.u = u1;
            pf[0] = c0.h;   // keys quad*8+0..7   (k-pos 0..31 of frag0)
            pf[1] = c1.h;   // keys 32+quad*8+0..7
        }
        // ---- denominator + PV (V' rows already mask-scaled) ----
        bf16x8 mf0 = *(const bf16x8*)&Ms[buf][quad*8];
        bf16x8 mf1 = *(const bf16x8*)&Ms[buf][32 + quad*8];
        __builtin_amdgcn_s_setprio(1);
        dacc = MFMA16(pf[0], mf0, dacc);
        dacc = MFMA16(pf[1], mf1, dacc);
        #pragma unroll
        for (int nj = 0; nj < 4; ++nj) {
            bf16x8 vf0 = *(const bf16x8*)&Vs[buf][nj*16 + q15][quad*8];
            bf16x8 vf1 = *(const bf16x8*)&Vs[buf][nj*16 + q15][32 + quad*8];
            oacc[nj] = MFMA16(pf[0], vf0, oacc[nj]);
            oacc[nj] = MFMA16(pf[1], vf1, oacc[nj]);
        }
        __builtin_amdgcn_s_setprio(0);
    }

    // epilogue: D rows quad*4+r = query; denom replicated across n lanes
    #pragma unroll
    for (int r = 0; r < 4; ++r) {
        float inv = 1.0f / (dacc[r] + 1e-8f);
        size_t row = ((size_t)b*S_LEN + q0 + wv*16 + quad*4 + r)*DMODEL
                   + h*DHEAD;
        #pragma unroll
        for (int nj = 0; nj < 4; ++nj)
            out[row + nj*16 + q15] = oacc[nj][r] * inv;
    }
}

// ---------------------------------------------------------------------------
extern "C" void kernel_launch(void* const* d_in, const int* in_sizes, int n_in,
                              void* d_out, int out_size, void* d_ws, size_t ws_size,
                              hipStream_t stream) {
    const float* Q    = (const float*)d_in[0];
    const float* msk  = (const float*)d_in[1];
    const float* W_Q  = (const float*)d_in[2];
    const float* b_Q  = (const float*)d_in[3];
    const float* W_K  = (const float*)d_in[4];
    const float* b_K  = (const float*)d_in[5];
    const float* W_V  = (const float*)d_in[6];
    const float* b_V  = (const float*)d_in[7];
    float* out = (float*)d_out;

    unsigned short* wsu = (unsigned short*)d_ws;
    unsigned short* Qbf = wsu;                                   // 4M elems
    unsigned short* Wbf = Qbf + (size_t)4096*1024;               // 3M
    unsigned short* qwb = Wbf + (size_t)3*1024*1024;             // 4M
    unsigned short* kwb = qwb + (size_t)4*1024*1024;             // 4M
    unsigned short* vtb = kwb + (size_t)4*1024*1024;             // 4M
    unsigned short* mbf = vtb + (size_t)4*1024*1024;             // 4K

    cvt_all<<<3586, 256, 0, stream>>>(Q, W_Q, W_K, W_V, msk, Qbf, Wbf, mbf);

    proj_mfma<<<dim3(8, 32, 3), 256, 0, stream>>>(
        Qbf, Wbf, b_Q, b_K, b_V, msk, qwb, kwb, vtb);

    attn_mfma<<<dim3(S_LEN/64, NH, BATCH), 256, 0, stream>>>(
        qwb, kwb, vtb, mbf, out);
}

// Round 3
// 164.717 us; speedup vs baseline: 1.1038x; 1.1038x over previous
//
#include <hip/hip_runtime.h>
#include <hip/hip_bf16.h>
#include <math.h>

#define BATCH  2
#define S_LEN  2048
#define DMODEL 1024
#define NH     16
#define DHEAD  64

typedef __attribute__((ext_vector_type(8))) short bf16x8;   // 8 bf16 = 4 VGPRs
typedef __attribute__((ext_vector_type(4))) float f32x4;

#define MFMA16(a,b,c) __builtin_amdgcn_mfma_f32_16x16x32_bf16((a),(b),(c),0,0,0)

// Q pre-scale: (1/sqrt(64)) * log2(e) so attention uses exp2 directly
#define QSCALE 0.18033688011110793f
#define EXP2F(x) __builtin_amdgcn_exp2f(x)

__device__ __forceinline__ unsigned int pkbf(float a, float b) {
    __hip_bfloat162 h = __float22bfloat162_rn(make_float2(a, b));
    union { __hip_bfloat162 h; unsigned int u; } v; v.h = h; return v.u;
}
__device__ __forceinline__ void gl2lds16(const void* g, void* l) {
    __builtin_amdgcn_global_load_lds(
        (const __attribute__((address_space(1))) void*)(g),
        (__attribute__((address_space(3))) void*)(l), 16, 0, 0);
}

// ---------------------------------------------------------------------------
// Single fused fp32->bf16 convert for Q, W_Q|W_K|W_V, mask. 8 elems/unit.
// Layout: units [0,524288) = Q; [524288,917504) = W (3x131072); tail = mask.
// ---------------------------------------------------------------------------
__global__ __launch_bounds__(256) void cvt_all(
    const float* __restrict__ Q,  const float* __restrict__ WQ,
    const float* __restrict__ WK, const float* __restrict__ WV,
    const float* __restrict__ msk,
    unsigned short* __restrict__ Qbf, unsigned short* __restrict__ Wbf,
    unsigned short* __restrict__ mbf)
{
    int i = blockIdx.x * blockDim.x + threadIdx.x;   // grid covers 918016 units
    const float* src;
    unsigned short* dst;
    int off;
    if (i < 524288) {
        src = Q; dst = Qbf; off = i;
    } else if (i < 917504) {
        int j = i - 524288;                  // [0, 393216)
        int which = j >> 17;                 // /131072
        src = (which == 0) ? WQ : ((which == 1) ? WK : WV);
        dst = Wbf + ((size_t)which << 20);   // which * 1048576
        off = j & 131071;
    } else {
        int j = i - 917504;
        if (j >= 512) return;
        src = msk; dst = mbf; off = j;
    }
    float4 a = ((const float4*)src)[2*off];
    float4 b = ((const float4*)src)[2*off + 1];
    uint4 o;
    o.x = pkbf(a.x, a.y); o.y = pkbf(a.z, a.w);
    o.z = pkbf(b.x, b.y); o.w = pkbf(b.z, b.w);
    ((uint4*)dst)[off] = o;
}

// ---------------------------------------------------------------------------
// Projection GEMM with folds:
//   z=0 -> qw [b,h,s,dk], output scaled by QSCALE (1/sqrt(dk) * log2e)
//   z=1 -> kw [b,h,s,dk]
//   z=2 -> vt [b,h,dv,s], output multiplied by mask[b][s] (V' = mask*V)
// 128x128 tile, BK=64, 4 waves, double-buffered LDS, 2-phase pipeline.
// XOR-swizzled LDS (linear gl2lds dest + pre-swizzled global source + swz read).
// XCD-bijective block remap (768 = 8*96).
// ---------------------------------------------------------------------------
__global__ __launch_bounds__(256) void proj_mfma(
    const unsigned short* __restrict__ Abf,   // [4096][1024]
    const unsigned short* __restrict__ Wbf,   // [3][1024][1024]
    const float* __restrict__ bQ, const float* __restrict__ bK,
    const float* __restrict__ bV, const float* __restrict__ mask,
    unsigned short* __restrict__ qw, unsigned short* __restrict__ kw,
    unsigned short* __restrict__ vt)
{
    __shared__ union {
        struct { unsigned short At[2][128*64]; unsigned short Bt[2][128*64]; } s; // 64 KB
        unsigned short Ct[128*132];     // epilogue transpose tile (33.8 KB, aliased)
    } sm;

    const int tid  = threadIdx.x;
    const int lane = tid & 63;
    const int wv   = tid >> 6;
    const int wm   = (wv >> 1) * 64;
    const int wn   = (wv & 1) * 64;
    const int q15  = lane & 15;
    const int quad = lane >> 4;

    // XCD-aware bijective remap: f = x + 8y + 256z in [0,768); xcd = f%8 owns
    // logical ids [xcd*96, xcd*96+96) = contiguous (z, m-panel) ranges.
    const int f  = blockIdx.x + (blockIdx.y << 3) + (blockIdx.z << 8);
    const int l  = (f & 7) * 96 + (f >> 3);
    const int z  = l >> 8;
    const int lr = l & 255;
    const int n0 = (lr & 7) * 128;
    const int m0 = (lr >> 3) * 128;

    const unsigned short* Wz = Wbf + (size_t)z * DMODEL * DMODEL;
    const float* bias = (z == 0) ? bQ : ((z == 1) ? bK : bV);

    f32x4 zero4 = {0.f, 0.f, 0.f, 0.f};
    f32x4 acc[4][4];
    #pragma unroll
    for (int i = 0; i < 4; ++i)
        #pragma unroll
        for (int j = 0; j < 4; ++j) acc[i][j] = zero4;

    #define STAGE_PROJ(BUF, K0)                                                \
        _Pragma("unroll")                                                      \
        for (int c = 0; c < 4; ++c) {                                          \
            int o   = tid * 16 + c * 4096;                                     \
            int row = o >> 7;                                                  \
            int lb  = (o & 127) ^ ((row & 7) << 4);                            \
            gl2lds16(Abf + (size_t)(m0 + row) * DMODEL + (K0) + (lb >> 1),     \
                     (char*)sm.s.At[BUF] + o);                                 \
            gl2lds16(Wz  + (size_t)(n0 + row) * DMODEL + (K0) + (lb >> 1),     \
                     (char*)sm.s.Bt[BUF] + o);                                 \
        }

    // prologue: fill buffer 0
    STAGE_PROJ(0, 0)
    __syncthreads();

    const int sw = (q15 & 7) << 4;   // read-side swizzle ((row&7)<<4; row&7 == q15&7)

    for (int t = 0; t < 16; ++t) {
        const int buf = t & 1;
        if (t < 15) { STAGE_PROJ(buf ^ 1, (t + 1) * 64) }   // in flight under compute

        bf16x8 af[4][2], bfr[4][2];
        #pragma unroll
        for (int i = 0; i < 4; ++i) {
            const char* pa = (const char*)sm.s.At[buf] + (wm + i*16 + q15) * 128;
            const char* pb = (const char*)sm.s.Bt[buf] + (wn + i*16 + q15) * 128;
            af[i][0]  = *(const bf16x8*)(pa + (( 0 + quad*16) ^ sw));
            af[i][1]  = *(const bf16x8*)(pa + ((64 + quad*16) ^ sw));
            bfr[i][0] = *(const bf16x8*)(pb + (( 0 + quad*16) ^ sw));
            bfr[i][1] = *(const bf16x8*)(pb + ((64 + quad*16) ^ sw));
        }

        if (z < 2) {
            #pragma unroll
            for (int ks = 0; ks < 2; ++ks)
                #pragma unroll
                for (int i = 0; i < 4; ++i)
                    #pragma unroll
                    for (int j = 0; j < 4; ++j)
                        acc[i][j] = MFMA16(bfr[j][ks], af[i][ks], acc[i][j]);
        } else {
            #pragma unroll
            for (int ks = 0; ks < 2; ++ks)
                #pragma unroll
                for (int i = 0; i < 4; ++i)
                    #pragma unroll
                    for (int j = 0; j < 4; ++j)
                        acc[i][j] = MFMA16(af[i][ks], bfr[j][ks], acc[i][j]);
        }
        __syncthreads();   // drains stage(t+1) vmcnt + fences buf reuse
    }
    #undef STAGE_PROJ

    // epilogue (Ct aliases At/Bt; last barrier above fenced all reads)
    if (z < 2) {
        const float qs = (z == 0) ? QSCALE : 1.0f;
        #pragma unroll
        for (int i = 0; i < 4; ++i) {
            int ml = wm + i*16 + q15;
            #pragma unroll
            for (int j = 0; j < 4; ++j) {
                int nl = wn + j*16 + quad*4;
                float4 b4 = *(const float4*)(bias + n0 + nl);
                f32x4 v = acc[i][j];
                uint2 u;
                u.x = pkbf((v.x + b4.x)*qs, (v.y + b4.y)*qs);
                u.y = pkbf((v.z + b4.z)*qs, (v.w + b4.w)*qs);
                *(uint2*)&sm.Ct[ml*132 + nl] = u;
            }
        }
    } else {
        #pragma unroll
        for (int i = 0; i < 4; ++i) {
            int ml = wm + i*16 + quad*4;
            int sg = m0 + ml;
            int b2 = sg >> 11, s0g = sg & 2047;
            float4 mk4 = *(const float4*)(mask + (size_t)b2*S_LEN + s0g);
            #pragma unroll
            for (int j = 0; j < 4; ++j) {
                int nl = wn + j*16 + q15;
                float bv = bias[n0 + nl];
                f32x4 v = acc[i][j];
                uint2 u;
                u.x = pkbf((v.x + bv)*mk4.x, (v.y + bv)*mk4.y);
                u.y = pkbf((v.z + bv)*mk4.z, (v.w + bv)*mk4.w);
                *(uint2*)&sm.Ct[nl*132 + ml] = u;
            }
        }
    }
    __syncthreads();

    {
        int row  = tid >> 1;
        int half = (tid & 1) * 64;
        const uint4* src = (const uint4*)&sm.Ct[row*132 + half];
        unsigned short* dst;
        if (z < 2) {
            unsigned short* outp = (z == 0) ? qw : kw;
            int mg = m0 + row;  int b2 = mg >> 11, s = mg & 2047;
            int n  = n0 + half; int hh = n >> 6;
            dst = outp + (((size_t)b2*NH + hh)*S_LEN + s)*DHEAD;
        } else {
            int n  = n0 + row;  int hh = n >> 6, dv = n & 63;
            int b2 = m0 >> 11, s0 = m0 & 2047;
            dst = vt + (((size_t)b2*NH + hh)*DHEAD + dv)*S_LEN + s0 + half;
        }
        #pragma unroll
        for (int c = 0; c < 8; ++c) ((uint4*)dst)[c] = src[c];
    }
}

// ---------------------------------------------------------------------------
// Attention: block = 128 queries x (h, b); 4 waves x 32 queries.
// [Round-3: reverted to 32 q/wave — round-2's 16 q/wave doubled per-CU LDS
//  read volume (~+15 us) since every wave streams the full K/V tile from LDS;
//  this kernel sits in the sum-of-pipes regime, so pipe VOLUME dominates.]
// XCD-bijective remap kept (proven: FETCH 69.7->12.3 MB): 512 = 8*64, each
// XCD owns 4 complete heads -> 2 MB K/V working set, L2-resident.
// K staged into LDS with rows PERMUTED by lambda(key) so the QK C-layout,
// exp'd and packed, IS the PV A-fragment in registers (no P LDS round-trip).
//   lambda(key) = (key>>5)*32 + ((key>>2)&1)*16 + ((key>>3)&3)*4 + (key&3)
// Q pre-scaled by QSCALE -> scores already in log2 domain -> v_exp_f32.
// V pre-multiplied by mask; denominator = P @ mask via MFMA; the mask
// fragment now lives in REGISTERS (16B global loads from L2-resident bf16
// mask, prefetched a tile ahead) -> no Ms LDS reads/writes, no tid<8 branch.
// s_setprio(1) wraps the MFMA clusters (T5).
// ---------------------------------------------------------------------------
__global__ __launch_bounds__(256, 2) void attn_mfma(
    const unsigned short* __restrict__ qw, const unsigned short* __restrict__ kw,
    const unsigned short* __restrict__ vt, const unsigned short* __restrict__ mbf,
    float* __restrict__ out)
{
    __shared__ __align__(16) unsigned short Ks[2][64][72];   // [perm key][d]
    __shared__ __align__(16) unsigned short Vs[2][64][72];   // [dv][key]

    const int tid  = threadIdx.x;
    const int lane = tid & 63;
    const int wv   = tid >> 6;
    const int q15  = lane & 15;
    const int quad = lane >> 4;

    // XCD-bijective remap (512 blocks = 8 XCDs x 64): XCD c owns lid in
    // [c*64, c*64+64) = heads [c*4, c*4+4), all 16 q-blocks of each.
    const int orig = blockIdx.x + (blockIdx.y << 4) + (blockIdx.z << 8);
    const int lid  = (orig & 7) * 64 + (orig >> 3);
    const int q0   = (lid & 15) * 128;
    const int head = lid >> 4;          // [0,32)
    const int h    = head & 15;
    const int b    = head >> 4;

    const size_t headoff = ((size_t)b * NH + h) * S_LEN * DHEAD;
    const unsigned short* qb = qw + headoff;
    const unsigned short* kb = kw + headoff;
    const unsigned short* vb = vt + headoff;          // [dv][s]
    const unsigned short* mb = mbf + (size_t)b * S_LEN;

    // Q fragments (B-operand): B[k=d at quad*8+j][n=query at lane&15]
    bf16x8 qf[2][2];
    #pragma unroll
    for (int qi = 0; qi < 2; ++qi) {
        const unsigned short* qr = qb + (size_t)(q0 + wv*32 + qi*16 + q15)*DHEAD;
        qf[qi][0] = *(const bf16x8*)(qr + quad*8);
        qf[qi][1] = *(const bf16x8*)(qr + 32 + quad*8);
    }

    const int srow = tid >> 3;          // 0..31 (key row for staging)
    const int scol = (tid & 7) * 8;     // 0..56
    // permuted LDS row for K (srow in [0,32); +32 row adds +32 to lambda)
    const int prow = ((srow >> 2) & 1) * 16 + ((srow >> 3) & 3) * 4 + (srow & 3);

    f32x4 zero4 = {0.f, 0.f, 0.f, 0.f};
    f32x4 oacc[2][4];
    f32x4 dacc[2];
    #pragma unroll
    for (int qi = 0; qi < 2; ++qi) {
        dacc[qi] = zero4;
        #pragma unroll
        for (int nj = 0; nj < 4; ++nj) oacc[qi][nj] = zero4;
    }

    // prologue: prefetch tile 0 into registers (K/V uint4, mask frags)
    uint4 kr0, kr1, vr0, vr1;
    kr0 = *(const uint4*)(kb + (size_t)(srow)     *DHEAD + scol);
    kr1 = *(const uint4*)(kb + (size_t)(srow + 32)*DHEAD + scol);
    vr0 = *(const uint4*)(vb + (size_t)(srow)     *S_LEN + scol);
    vr1 = *(const uint4*)(vb + (size_t)(srow + 32)*S_LEN + scol);
    bf16x8 mc0 = *(const bf16x8*)(mb + quad*8);
    bf16x8 mc1 = *(const bf16x8*)(mb + 32 + quad*8);

    for (int t = 0; t < 32; ++t) {
        const int buf = t & 1;
        const int k0  = t * 64;
        // commit staged regs to LDS[buf]
        *(uint4*)&Ks[buf][prow][scol]      = kr0;
        *(uint4*)&Ks[buf][prow + 32][scol] = kr1;
        *(uint4*)&Vs[buf][srow][scol]      = vr0;
        *(uint4*)&Vs[buf][srow + 32][scol] = vr1;
        // issue prefetch for tile t+1 (clamped; overlaps compute below)
        const int kn = (t < 31) ? k0 + 64 : 0;
        kr0 = *(const uint4*)(kb + (size_t)(kn + srow)     *DHEAD + scol);
        kr1 = *(const uint4*)(kb + (size_t)(kn + srow + 32)*DHEAD + scol);
        vr0 = *(const uint4*)(vb + (size_t)(srow)     *S_LEN + kn + scol);
        vr1 = *(const uint4*)(vb + (size_t)(srow + 32)*S_LEN + kn + scol);
        bf16x8 mn0 = *(const bf16x8*)(mb + kn + quad*8);
        bf16x8 mn1 = *(const bf16x8*)(mb + kn + 32 + quad*8);
        __syncthreads();

        // ---- QK^T: 4 tiles; tile ks reg r = key quad*8+r+4*(ks&1)+32*(ks>>1)
        f32x4 s[2][4];
        __builtin_amdgcn_s_setprio(1);
        #pragma unroll
        for (int ks = 0; ks < 4; ++ks) {
            bf16x8 kf0 = *(const bf16x8*)&Ks[buf][ks*16 + q15][quad*8];
            bf16x8 kf1 = *(const bf16x8*)&Ks[buf][ks*16 + q15][32 + quad*8];
            #pragma unroll
            for (int qi = 0; qi < 2; ++qi) {
                f32x4 a = MFMA16(kf0, qf[qi][0], zero4);
                s[qi][ks] = MFMA16(kf1, qf[qi][1], a);
            }
        }
        __builtin_amdgcn_s_setprio(0);
        // ---- exp2 + pack: registers ARE the PV A-fragments ----
        bf16x8 pf[2][2];
        #pragma unroll
        for (int qi = 0; qi < 2; ++qi) {
            uint4 u0, u1;
            u0.x = pkbf(EXP2F(s[qi][0][0]), EXP2F(s[qi][0][1]));
            u0.y = pkbf(EXP2F(s[qi][0][2]), EXP2F(s[qi][0][3]));
            u0.z = pkbf(EXP2F(s[qi][1][0]), EXP2F(s[qi][1][1]));
            u0.w = pkbf(EXP2F(s[qi][1][2]), EXP2F(s[qi][1][3]));
            u1.x = pkbf(EXP2F(s[qi][2][0]), EXP2F(s[qi][2][1]));
            u1.y = pkbf(EXP2F(s[qi][2][2]), EXP2F(s[qi][2][3]));
            u1.z = pkbf(EXP2F(s[qi][3][0]), EXP2F(s[qi][3][1]));
            u1.w = pkbf(EXP2F(s[qi][3][2]), EXP2F(s[qi][3][3]));
            union { uint4 u; bf16x8 h; } c0, c1;
            c0.u = u0; c1.u = u1;
            pf[qi][0] = c0.h;   // keys quad*8+0..7   (k-pos 0..31 of frag0)
            pf[qi][1] = c1.h;   // keys 32+quad*8+0..7
        }
        // ---- denominator: P @ mask (mask frags in registers) ----
        __builtin_amdgcn_s_setprio(1);
        #pragma unroll
        for (int qi = 0; qi < 2; ++qi) {
            dacc[qi] = MFMA16(pf[qi][0], mc0, dacc[qi]);
            dacc[qi] = MFMA16(pf[qi][1], mc1, dacc[qi]);
        }
        // ---- PV: V' rows (already mask-scaled) from LDS ----
        #pragma unroll
        for (int nj = 0; nj < 4; ++nj) {
            bf16x8 vf0 = *(const bf16x8*)&Vs[buf][nj*16 + q15][quad*8];
            bf16x8 vf1 = *(const bf16x8*)&Vs[buf][nj*16 + q15][32 + quad*8];
            #pragma unroll
            for (int qi = 0; qi < 2; ++qi) {
                oacc[qi][nj] = MFMA16(pf[qi][0], vf0, oacc[qi][nj]);
                oacc[qi][nj] = MFMA16(pf[qi][1], vf1, oacc[qi][nj]);
            }
        }
        __builtin_amdgcn_s_setprio(0);
        // rotate mask prefetch
        mc0 = mn0; mc1 = mn1;
    }

    // epilogue: D rows quad*4+r = query; denom replicated across n lanes
    #pragma unroll
    for (int qi = 0; qi < 2; ++qi)
        #pragma unroll
        for (int r = 0; r < 4; ++r) {
            float inv = 1.0f / (dacc[qi][r] + 1e-8f);
            size_t row = ((size_t)b*S_LEN + q0 + wv*32 + qi*16 + quad*4 + r)*DMODEL
                       + h*DHEAD;
            #pragma unroll
            for (int nj = 0; nj < 4; ++nj)
                out[row + nj*16 + q15] = oacc[qi][nj][r] * inv;
        }
}

// ---------------------------------------------------------------------------
extern "C" void kernel_launch(void* const* d_in, const int* in_sizes, int n_in,
                              void* d_out, int out_size, void* d_ws, size_t ws_size,
                              hipStream_t stream) {
    const float* Q    = (const float*)d_in[0];
    const float* msk  = (const float*)d_in[1];
    const float* W_Q  = (const float*)d_in[2];
    const float* b_Q  = (const float*)d_in[3];
    const float* W_K  = (const float*)d_in[4];
    const float* b_K  = (const float*)d_in[5];
    const float* W_V  = (const float*)d_in[6];
    const float* b_V  = (const float*)d_in[7];
    float* out = (float*)d_out;

    unsigned short* wsu = (unsigned short*)d_ws;
    unsigned short* Qbf = wsu;                                   // 4M elems
    unsigned short* Wbf = Qbf + (size_t)4096*1024;               // 3M
    unsigned short* qwb = Wbf + (size_t)3*1024*1024;             // 4M
    unsigned short* kwb = qwb + (size_t)4*1024*1024;             // 4M
    unsigned short* vtb = kwb + (size_t)4*1024*1024;             // 4M
    unsigned short* mbf = vtb + (size_t)4*1024*1024;             // 4K

    cvt_all<<<3586, 256, 0, stream>>>(Q, W_Q, W_K, W_V, msk, Qbf, Wbf, mbf);

    proj_mfma<<<dim3(8, 32, 3), 256, 0, stream>>>(
        Qbf, Wbf, b_Q, b_K, b_V, msk, qwb, kwb, vtb);

    attn_mfma<<<dim3(S_LEN/128, NH, BATCH), 256, 0, stream>>>(
        qwb, kwb, vtb, mbf, out);
}